// Round 1
// baseline (125.420 us; speedup 1.0000x reference)
//
#include <hip/hip_runtime.h>
#include <stdint.h>

// Problem: out[b,i,s] = (||w_i||^2 - 2*sum_o w[i,o]x[b,o,s] + ||x_{b,:,s}||^2) / K
// B=4, M=IN_DIM=4096, K=OUT_DIM=1024, N=S=2048. fp32 in/out.
// Strategy: bf16 MFMA GEMM for the cross term (threshold 2.45e-2 >> bf16 error
// after /K), fp32 norm terms, fused epilogue.

#define M_DIM 4096
#define K_DIM 1024
#define N_DIM 2048
#define B_DIM 4

#define BM 128
#define BN 128
#define BK 32

typedef __attribute__((ext_vector_type(8))) __bf16 bf16x8;
typedef __attribute__((ext_vector_type(4))) float f32x4;

__device__ __forceinline__ ushort f2bf(float f) {
  uint32_t u = __float_as_uint(f);
  uint32_t r = (u + 0x7fffu + ((u >> 16) & 1u)) >> 16;  // round-nearest-even
  return (ushort)r;
}
__device__ __forceinline__ float bf2f(ushort u) {
  return __uint_as_float(((uint32_t)u) << 16);
}

// -------- prep_w: w (f32, [M][K]) -> wbf (bf16 [M][K]) + w2[i] = sum_o w^2 --
__global__ __launch_bounds__(256) void prep_w(const float* __restrict__ w,
                                              ushort* __restrict__ wbf,
                                              float* __restrict__ w2) {
  const int i = blockIdx.x;   // 4096 rows
  const int t = threadIdx.x;  // 256 threads, 4 floats each = 1024 = K
  float4 v = ((const float4*)(w + (size_t)i * K_DIM))[t];
  float ss = v.x * v.x + v.y * v.y + v.z * v.z + v.w * v.w;
  ushort4 o = make_ushort4(f2bf(v.x), f2bf(v.y), f2bf(v.z), f2bf(v.w));
  ((ushort4*)(wbf + (size_t)i * K_DIM))[t] = o;
#pragma unroll
  for (int off = 32; off > 0; off >>= 1) ss += __shfl_down(ss, off);
  __shared__ float red[4];
  if ((t & 63) == 0) red[t >> 6] = ss;
  __syncthreads();
  if (t == 0) w2[i] = red[0] + red[1] + red[2] + red[3];
}

// -------- prep_x: x (f32 [B][K][N]) -> xbT (bf16 [B][N][K]) + x2[b,s] -------
// 64x64 tiles through LDS so both global read and global write are coalesced.
__global__ __launch_bounds__(256) void prep_x(const float* __restrict__ x,
                                              ushort* __restrict__ xbT,
                                              float* __restrict__ x2) {
  __shared__ ushort tile[64][68];  // [o_local][s_local], padded
  const int b = blockIdx.z;
  const int o0 = blockIdx.y * 64;
  const int s0 = blockIdx.x * 64;
  const int t = threadIdx.x;
  const int tr = t >> 4;  // 0..15
  const int tc = t & 15;  // 0..15

  // load: rows = o, cols = s (coalesced float4 on s)
#pragma unroll
  for (int p = 0; p < 4; ++p) {
    const int r = p * 16 + tr;  // o_local
    float4 v = ((const float4*)(x + ((size_t)(b * K_DIM + o0 + r)) * N_DIM + s0))[tc];
    tile[r][tc * 4 + 0] = f2bf(v.x);
    tile[r][tc * 4 + 1] = f2bf(v.y);
    tile[r][tc * 4 + 2] = f2bf(v.z);
    tile[r][tc * 4 + 3] = f2bf(v.w);
  }
  __syncthreads();

  // write: rows = s, cols = o (coalesced ushort4 on o); also partial x2
#pragma unroll
  for (int p = 0; p < 4; ++p) {
    const int s = p * 16 + tr;  // s_local
    ushort u0 = tile[tc * 4 + 0][s];
    ushort u1 = tile[tc * 4 + 1][s];
    ushort u2 = tile[tc * 4 + 2][s];
    ushort u3 = tile[tc * 4 + 3][s];
    float f0 = bf2f(u0), f1 = bf2f(u1), f2 = bf2f(u2), f3 = bf2f(u3);
    float ss = f0 * f0 + f1 * f1 + f2 * f2 + f3 * f3;
    // reduce across the 16 lanes sharing this s (consecutive lanes in wave)
#pragma unroll
    for (int m = 1; m < 16; m <<= 1) ss += __shfl_xor(ss, m);
    if (tc == 0) atomicAdd(&x2[b * N_DIM + s0 + s], ss);
    *(ushort4*)(xbT + ((size_t)(b * N_DIM + s0 + s)) * K_DIM + o0 + tc * 4) =
        make_ushort4(u0, u1, u2, u3);
  }
}

// -------- GEMM + fused epilogue (m97 structure) ------------------------------
typedef const __attribute__((address_space(1))) uint32_t* gp_t;
typedef __attribute__((address_space(3))) uint32_t* lp_t;

__device__ __forceinline__ void gload_lds16(const void* g, const void* l) {
  __builtin_amdgcn_global_load_lds((gp_t)(uintptr_t)g,
                                   (lp_t)(uint32_t)(uintptr_t)l, 16, 0, 0);
}

__global__ __launch_bounds__(256) void gemm_mse(
    const ushort* __restrict__ wbf, const ushort* __restrict__ xbT,
    const float* __restrict__ w2, const float* __restrict__ x2,
    float* __restrict__ out) {
  __shared__ ushort As[BM * BK];  // [128][32], k-contiguous
  __shared__ ushort Bs[BN * BK];  // [128][32], k-contiguous (xT rows = s)
  const int t = threadIdx.x;
  const int wid = t >> 6;
  const int lane = t & 63;
  const int wm = wid >> 1;  // 2x2 waves of 64x64
  const int wn = wid & 1;
  const int b = blockIdx.z;
  const int it = blockIdx.x;
  const int st = blockIdx.y;

  const ushort* Ag = wbf + (size_t)it * BM * K_DIM;
  const ushort* Bg = xbT + ((size_t)b * N_DIM + (size_t)st * BN) * K_DIM;

  // staging geometry: per wave-instr 64 lanes x 16B = 1024B = 16 rows of BK=32
  const int srow = wid * 32 + (lane >> 2);
  const int scol = (lane & 3) * 8;

  const int r = lane & 15;  // fragment row/col within 16
  const int g = lane >> 4;  // k-octet 0..3

  f32x4 acc[4][4] = {};

  for (int k0 = 0; k0 < K_DIM; k0 += BK) {
    gload_lds16(Ag + (size_t)srow * K_DIM + k0 + scol, As + (wid * 2 + 0) * 512);
    gload_lds16(Ag + (size_t)(srow + 16) * K_DIM + k0 + scol, As + (wid * 2 + 1) * 512);
    gload_lds16(Bg + (size_t)srow * K_DIM + k0 + scol, Bs + (wid * 2 + 0) * 512);
    gload_lds16(Bg + (size_t)(srow + 16) * K_DIM + k0 + scol, Bs + (wid * 2 + 1) * 512);
    __syncthreads();

    bf16x8 af[4], bfr[4];
#pragma unroll
    for (int mi = 0; mi < 4; ++mi)
      af[mi] = *(const bf16x8*)(As + (wm * 64 + mi * 16 + r) * BK + g * 8);
#pragma unroll
    for (int ni = 0; ni < 4; ++ni)
      bfr[ni] = *(const bf16x8*)(Bs + (wn * 64 + ni * 16 + r) * BK + g * 8);
#pragma unroll
    for (int mi = 0; mi < 4; ++mi)
#pragma unroll
      for (int ni = 0; ni < 4; ++ni)
        acc[mi][ni] = __builtin_amdgcn_mfma_f32_16x16x32_bf16(af[mi], bfr[ni],
                                                              acc[mi][ni], 0, 0, 0);
    __syncthreads();
  }

  // epilogue: out = (w2[i] - 2*wx + x2[b,s]) / K
  const float inv = 1.0f / (float)K_DIM;
  float* outp = out + ((size_t)b * M_DIM + (size_t)it * BM) * N_DIM + (size_t)st * BN;
  const float* w2p = w2 + it * BM;
  const float* x2p = x2 + b * N_DIM + st * BN;
#pragma unroll
  for (int ni = 0; ni < 4; ++ni) {
    const int col = wn * 64 + ni * 16 + r;
    const float xv = x2p[col];
#pragma unroll
    for (int mi = 0; mi < 4; ++mi) {
#pragma unroll
      for (int j = 0; j < 4; ++j) {
        const int row = wm * 64 + mi * 16 + g * 4 + j;
        outp[(size_t)row * N_DIM + col] = (w2p[row] - 2.0f * acc[mi][ni][j] + xv) * inv;
      }
    }
  }
}

// -------- launcher -----------------------------------------------------------
extern "C" void kernel_launch(void* const* d_in, const int* in_sizes, int n_in,
                              void* d_out, int out_size, void* d_ws, size_t ws_size,
                              hipStream_t stream) {
  const float* x = (const float*)d_in[0];  // (4, 1024, 2048)
  const float* w = (const float*)d_in[1];  // (4096, 1024)
  float* out = (float*)d_out;              // (4, 4096, 2048)
  char* ws = (char*)d_ws;
  // workspace: wbf 8MB | xbT 16MB | w2 16KB | x2 32KB  (~24.05 MB total)
  ushort* wbf = (ushort*)ws;
  ushort* xbT = (ushort*)(ws + (size_t)(8 << 20));
  float* w2 = (float*)(ws + (size_t)(24 << 20));
  float* x2 = w2 + M_DIM;

  hipMemsetAsync(x2, 0, B_DIM * N_DIM * sizeof(float), stream);
  prep_w<<<dim3(M_DIM), dim3(256), 0, stream>>>(w, wbf, w2);
  prep_x<<<dim3(N_DIM / 64, K_DIM / 64, B_DIM), dim3(256), 0, stream>>>(x, xbT, x2);
  gemm_mse<<<dim3(M_DIM / BM, N_DIM / BN, B_DIM), dim3(256), 0, stream>>>(wbf, xbT,
                                                                          w2, x2, out);
}

// Round 2
// 105.596 us; speedup vs baseline: 1.1877x; 1.1877x over previous
//
#include <hip/hip_runtime.h>
#include <stdint.h>

// out[b,i,s] = (||w_i||^2 - 2*sum_o w[i,o]x[b,o,s] + ||x_{b,:,s}||^2) / K
// B=4, M=4096, K=1024, N=2048. fp32 in/out. bf16 MFMA for cross term.
// GEMM: 256x256 tile, BK=32, 8 waves, quad-buffered LDS (128KB), counted
// vmcnt(8), raw s_barrier, XOR-swizzled LDS (both-sides), setprio, XCD swizzle.

#define M_DIM 4096
#define K_DIM 1024
#define N_DIM 2048
#define B_DIM 4

#define BM 256
#define BN 256
#define BK 32
#define NKT (K_DIM / BK)  // 32 K-tiles
#define MT (M_DIM / BM)   // 16
#define NT (N_DIM / BN)   // 8

typedef __attribute__((ext_vector_type(8))) __bf16 bf16x8;
typedef __attribute__((ext_vector_type(4))) float f32x4;

__device__ __forceinline__ ushort f2bf(float f) {
  uint32_t u = __float_as_uint(f);
  uint32_t r = (u + 0x7fffu + ((u >> 16) & 1u)) >> 16;  // RNE
  return (ushort)r;
}
__device__ __forceinline__ float bf2f(ushort u) {
  return __uint_as_float(((uint32_t)u) << 16);
}

// -------- prep_w -------------------------------------------------------------
__global__ __launch_bounds__(256) void prep_w(const float* __restrict__ w,
                                              ushort* __restrict__ wbf,
                                              float* __restrict__ w2) {
  const int i = blockIdx.x;
  const int t = threadIdx.x;
  float4 v = ((const float4*)(w + (size_t)i * K_DIM))[t];
  float ss = v.x * v.x + v.y * v.y + v.z * v.z + v.w * v.w;
  ushort4 o = make_ushort4(f2bf(v.x), f2bf(v.y), f2bf(v.z), f2bf(v.w));
  ((ushort4*)(wbf + (size_t)i * K_DIM))[t] = o;
#pragma unroll
  for (int off = 32; off > 0; off >>= 1) ss += __shfl_down(ss, off);
  __shared__ float red[4];
  if ((t & 63) == 0) red[t >> 6] = ss;
  __syncthreads();
  if (t == 0) w2[i] = red[0] + red[1] + red[2] + red[3];
}

// -------- prep_x -------------------------------------------------------------
__global__ __launch_bounds__(256) void prep_x(const float* __restrict__ x,
                                              ushort* __restrict__ xbT,
                                              float* __restrict__ x2) {
  __shared__ ushort tile[64][68];
  const int b = blockIdx.z;
  const int o0 = blockIdx.y * 64;
  const int s0 = blockIdx.x * 64;
  const int t = threadIdx.x;
  const int tr = t >> 4;
  const int tc = t & 15;
#pragma unroll
  for (int p = 0; p < 4; ++p) {
    const int r = p * 16 + tr;
    float4 v = ((const float4*)(x + ((size_t)(b * K_DIM + o0 + r)) * N_DIM + s0))[tc];
    tile[r][tc * 4 + 0] = f2bf(v.x);
    tile[r][tc * 4 + 1] = f2bf(v.y);
    tile[r][tc * 4 + 2] = f2bf(v.z);
    tile[r][tc * 4 + 3] = f2bf(v.w);
  }
  __syncthreads();
#pragma unroll
  for (int p = 0; p < 4; ++p) {
    const int s = p * 16 + tr;
    ushort u0 = tile[tc * 4 + 0][s];
    ushort u1 = tile[tc * 4 + 1][s];
    ushort u2 = tile[tc * 4 + 2][s];
    ushort u3 = tile[tc * 4 + 3][s];
    float f0 = bf2f(u0), f1 = bf2f(u1), f2 = bf2f(u2), f3 = bf2f(u3);
    float ss = f0 * f0 + f1 * f1 + f2 * f2 + f3 * f3;
#pragma unroll
    for (int m = 1; m < 16; m <<= 1) ss += __shfl_xor(ss, m);
    if (tc == 0) atomicAdd(&x2[b * N_DIM + s0 + s], ss);
    *(ushort4*)(xbT + ((size_t)(b * N_DIM + s0 + s)) * K_DIM + o0 + tc * 4) =
        make_ushort4(u0, u1, u2, u3);
  }
}

// -------- GEMM ---------------------------------------------------------------
typedef const __attribute__((address_space(1))) uint32_t* gp_t;
typedef __attribute__((address_space(3))) uint32_t* lp_t;

__device__ __forceinline__ void gload_lds16(const void* g, const void* l) {
  __builtin_amdgcn_global_load_lds((gp_t)(uintptr_t)g,
                                   (lp_t)(uint32_t)(uintptr_t)l, 16, 0, 0);
}

#define MFMA(a, b, c) __builtin_amdgcn_mfma_f32_16x16x32_bf16((a), (b), (c), 0, 0, 0)
#define FENCE() asm volatile("" ::: "memory")

__global__ __launch_bounds__(512, 2) void gemm_mse(
    const ushort* __restrict__ wbf, const ushort* __restrict__ xbT,
    const float* __restrict__ w2, const float* __restrict__ x2,
    float* __restrict__ out) {
  // LDS: A bufs 4x16KB at [0,64K), B bufs 4x16KB at [64K,128K)
  __shared__ __align__(16) char smem[131072];
  const int tid = threadIdx.x;
  const int wid = tid >> 6;
  const int lane = tid & 63;
  const int laneR = lane & 15;
  const int g = lane >> 4;
  const int wm = wid >> 2;  // 0..1
  const int wn = wid & 3;   // 0..3

  // XCD-aware block swizzle (512 blocks, 512%8==0 -> bijective)
  const int bid = blockIdx.x;
  const int swz = (bid & 7) * (MT * NT * B_DIM / 8) + (bid >> 3);
  const int m = swz & (MT - 1);
  const int nb = swz >> 4;
  const int n = nb & (NT - 1);
  const int bz = nb >> 3;

  const ushort* Ag = wbf + (size_t)m * BM * K_DIM;
  const ushort* Bg = xbT + ((size_t)bz * N_DIM + (size_t)n * BN) * K_DIM;

  // ---- staging geometry: slot s -> phys byte p=s*16; conceptual lin = p ^
  // (((p>>7)&3)<<4); row = lin>>6, col = (lin&63)>>1  (rows of 32 bf16 = 64B)
  const int p0 = tid * 16, p1 = (tid + 512) * 16;
  const int li0 = p0 ^ (((p0 >> 7) & 3) << 4);
  const int li1 = p1 ^ (((p1 >> 7) & 3) << 4);
  const size_t gOff0 = (size_t)(li0 >> 6) * K_DIM + ((li0 & 63) >> 1);
  const size_t gOff1 = (size_t)(li1 >> 6) * K_DIM + ((li1 & 63) >> 1);
  // wave-uniform LDS staging bases (bytes, + buf*16384 at use)
  const int stA0 = wid * 1024, stA1 = 8192 + wid * 1024;
  const int stB0 = 65536 + wid * 1024, stB1 = 65536 + 8192 + wid * 1024;

#define STAGE_A(tt)                                              \
  {                                                              \
    const int bo_ = ((tt) & 3) * 16384;                          \
    const int ko_ = (tt) * BK;                                   \
    gload_lds16(Ag + gOff0 + ko_, smem + bo_ + stA0);            \
    gload_lds16(Ag + gOff1 + ko_, smem + bo_ + stA1);            \
  }
#define STAGE_B(tt)                                              \
  {                                                              \
    const int bo_ = ((tt) & 3) * 16384;                          \
    const int ko_ = (tt) * BK;                                   \
    gload_lds16(Bg + gOff0 + ko_, smem + bo_ + stB0);            \
    gload_lds16(Bg + gOff1 + ko_, smem + bo_ + stB1);            \
  }

  // ---- fragment read bases. lin = row*64 + g*16; swizzle mask depends only
  // on laneR (bits 7..8 of lin = (laneR>>1)&3 for 16-aligned row blocks)
  const int mask = ((laneR >> 1) & 3) << 4;
  const int baseA = ((((wm * 128 + laneR) << 6) | (g << 4)) ^ mask);
  const int baseB = 65536 + ((((wn * 64 + laneR) << 6) | (g << 4)) ^ mask);

#define LDA(mi, bo) (*(const bf16x8*)(smem + (bo) + baseA + (mi)*1024))
#define LDB(ni, bo) (*(const bf16x8*)(smem + (bo) + baseB + (ni)*1024))

  f32x4 acc[8][4] = {};

  // ---- prologue: stage tiles 0,1,2 (12 loads/wave); tile 0 landed at vmcnt(8)
  STAGE_A(0); STAGE_B(0);
  STAGE_A(1); STAGE_B(1);
  STAGE_A(2); STAGE_B(2);
  asm volatile("s_waitcnt vmcnt(8)" ::: "memory");
  __builtin_amdgcn_s_barrier();
  FENCE();

  for (int t = 0; t < NKT; ++t) {
    const int bo = (t & 3) * 16384;
    // ======== phase 1: frag-read A[0-3],B[0-3]; stage A(t+3); mfma Q-low ====
    bf16x8 a0 = LDA(0, bo), a1 = LDA(1, bo), a2 = LDA(2, bo), a3 = LDA(3, bo);
    bf16x8 b0 = LDB(0, bo), b1 = LDB(1, bo), b2 = LDB(2, bo), b3 = LDB(3, bo);
    if (t < NKT - 3) STAGE_A(t + 3);
    FENCE();
    __builtin_amdgcn_s_barrier();
    FENCE();
    __builtin_amdgcn_s_setprio(1);
    acc[0][0] = MFMA(a0, b0, acc[0][0]);
    acc[0][1] = MFMA(a0, b1, acc[0][1]);
    acc[0][2] = MFMA(a0, b2, acc[0][2]);
    acc[0][3] = MFMA(a0, b3, acc[0][3]);
    acc[1][0] = MFMA(a1, b0, acc[1][0]);
    acc[1][1] = MFMA(a1, b1, acc[1][1]);
    acc[1][2] = MFMA(a1, b2, acc[1][2]);
    acc[1][3] = MFMA(a1, b3, acc[1][3]);
    acc[2][0] = MFMA(a2, b0, acc[2][0]);
    acc[2][1] = MFMA(a2, b1, acc[2][1]);
    acc[2][2] = MFMA(a2, b2, acc[2][2]);
    acc[2][3] = MFMA(a2, b3, acc[2][3]);
    acc[3][0] = MFMA(a3, b0, acc[3][0]);
    acc[3][1] = MFMA(a3, b1, acc[3][1]);
    acc[3][2] = MFMA(a3, b2, acc[3][2]);
    acc[3][3] = MFMA(a3, b3, acc[3][3]);
    __builtin_amdgcn_s_setprio(0);
    FENCE();
    __builtin_amdgcn_s_barrier();
    FENCE();
    // ======== phase 2: frag-read A[4-7]; stage B(t+3); vmcnt(8); mfma Q-high
    bf16x8 a4 = LDA(4, bo), a5 = LDA(5, bo), a6 = LDA(6, bo), a7 = LDA(7, bo);
    if (t < NKT - 3) STAGE_B(t + 3);
    // counted wait: 8 outstanding = tiles t+2,t+3 in flight; tile t+1 landed.
    asm volatile("s_waitcnt vmcnt(8)" ::: "memory");
    __builtin_amdgcn_s_barrier();
    FENCE();
    __builtin_amdgcn_s_setprio(1);
    acc[4][0] = MFMA(a4, b0, acc[4][0]);
    acc[4][1] = MFMA(a4, b1, acc[4][1]);
    acc[4][2] = MFMA(a4, b2, acc[4][2]);
    acc[4][3] = MFMA(a4, b3, acc[4][3]);
    acc[5][0] = MFMA(a5, b0, acc[5][0]);
    acc[5][1] = MFMA(a5, b1, acc[5][1]);
    acc[5][2] = MFMA(a5, b2, acc[5][2]);
    acc[5][3] = MFMA(a5, b3, acc[5][3]);
    acc[6][0] = MFMA(a6, b0, acc[6][0]);
    acc[6][1] = MFMA(a6, b1, acc[6][1]);
    acc[6][2] = MFMA(a6, b2, acc[6][2]);
    acc[6][3] = MFMA(a6, b3, acc[6][3]);
    acc[7][0] = MFMA(a7, b0, acc[7][0]);
    acc[7][1] = MFMA(a7, b1, acc[7][1]);
    acc[7][2] = MFMA(a7, b2, acc[7][2]);
    acc[7][3] = MFMA(a7, b3, acc[7][3]);
    __builtin_amdgcn_s_setprio(0);
    FENCE();
    __builtin_amdgcn_s_barrier();
    FENCE();
  }

  // ---- epilogue: out = (w2[i] - 2*acc + x2[b,s]) / K
  const float inv = 1.0f / (float)K_DIM;
  const int rowb = m * BM + wm * 128 + g * 4;  // + mi*16 + j
  const int colb = n * BN + wn * 64 + laneR;   // + ni*16
  float xv[4];
#pragma unroll
  for (int ni = 0; ni < 4; ++ni) xv[ni] = x2[bz * N_DIM + colb + ni * 16];
  float* outp = out + (size_t)bz * M_DIM * N_DIM;
#pragma unroll
  for (int mi = 0; mi < 8; ++mi) {
#pragma unroll
    for (int j = 0; j < 4; ++j) {
      const int row = rowb + mi * 16 + j;
      const float wv = w2[row];
      float* orow = outp + (size_t)row * N_DIM + colb;
#pragma unroll
      for (int ni = 0; ni < 4; ++ni)
        orow[ni * 16] = (wv - 2.0f * acc[mi][ni][j] + xv[ni]) * inv;
    }
  }
#undef STAGE_A
#undef STAGE_B
#undef LDA
#undef LDB
}

// -------- launcher -----------------------------------------------------------
extern "C" void kernel_launch(void* const* d_in, const int* in_sizes, int n_in,
                              void* d_out, int out_size, void* d_ws, size_t ws_size,
                              hipStream_t stream) {
  const float* x = (const float*)d_in[0];  // (4, 1024, 2048)
  const float* w = (const float*)d_in[1];  // (4096, 1024)
  float* out = (float*)d_out;              // (4, 4096, 2048)
  char* ws = (char*)d_ws;
  ushort* wbf = (ushort*)ws;                        // 8 MB
  ushort* xbT = (ushort*)(ws + (size_t)(8 << 20));  // 16 MB
  float* w2 = (float*)(ws + (size_t)(24 << 20));    // 16 KB
  float* x2 = w2 + M_DIM;                           // 32 KB

  hipMemsetAsync(x2, 0, B_DIM * N_DIM * sizeof(float), stream);
  prep_w<<<dim3(M_DIM), dim3(256), 0, stream>>>(w, wbf, w2);
  prep_x<<<dim3(N_DIM / 64, K_DIM / 64, B_DIM), dim3(256), 0, stream>>>(x, xbT, x2);
  gemm_mse<<<dim3(MT * NT * B_DIM), dim3(512), 0, stream>>>(wbf, xbT, w2, x2, out);
}